// Round 7
// baseline (37.728 us; speedup 1.0000x reference)
//
#include <hip/hip_runtime.h>

// YOLOv3 dense decode, 3 scales. Inputs (f32):
//  d_in[0] output_13 [32,255,13,13], d_in[1] output_26 [32,255,26,26],
//  d_in[2] output_52 [32,255,52,52], d_in[3..5] anchors [3,2] each,
//  d_in[6] thresh scalar.
// Output (f32 flat): boxes [340704,6] then valid [340704] (0.0/1.0).
//
// Round 7 probe: distinguish latency-bound vs BW-ceiling.
//  - 1 output row per thread, thread id == output row -> no tail, writes are
//    contiguous 1536B runs per wave (float2 stores, 8B-aligned).
//  - 85 scalar channel loads per thread, class loop in EXPLICIT 16-deep
//    batches (16 independent dests live before any fmax consume) -> forces
//    many outstanding loads per wave.
//  - 5324 waves (4x the float4 variant) at modest VGPR -> high occupancy.
//  In-flight bytes/CU should rise ~4-8x vs Round 2; if time doesn't drop,
//  the ~4 TB/s effective read rate is a pattern ceiling -> roofline.

constexpr int NCLS  = 80;
constexpr int BATCH = 32;
constexpr int HW13  = 169;
constexpr int HW26  = 676;
constexpr int HW52  = 2704;
constexpr int N13   = BATCH * 3 * HW13;   // 16224
constexpr int N26   = BATCH * 3 * HW26;   // 64896
constexpr int N52   = BATCH * 3 * HW52;   // 259584
constexpr int NTOT  = N13 + N26 + N52;    // 340704

__device__ __forceinline__ float sigm(float x) { return 1.0f / (1.0f + expf(-x)); }

template <int HW, int W>
__device__ __forceinline__ void decode_row(
    const float* __restrict__ in, const float* __restrict__ anc,
    float t, int li, int row, float th,
    float* __restrict__ boxes, float* __restrict__ valid)
{
    // reference row order within a scale: row = (b*HW + hw)*3 + a, a fastest
    const int a   = li % 3;
    const int pos = li / 3;
    const int hw  = pos % HW;
    const int b   = pos / HW;
    const int x   = hw % W;
    const int y   = hw / W;

    const float* p = in + (size_t)(b * 255 + a * 85) * HW + hw;

    const float t0 = p[0];
    const float t1 = p[(size_t)1 * HW];
    const float t2 = p[(size_t)2 * HW];
    const float t3 = p[(size_t)3 * HW];
    const float t4 = p[(size_t)4 * HW];

    float best = p[(size_t)5 * HW];
    int   cls  = 0;

    // classes 1..79 in batches of 16: all 16 loads issued (independent dests)
    // before the reduction consumes them -> ~16 outstanding VMEM per wave.
#pragma unroll
    for (int k0 = 1; k0 < NCLS; k0 += 16) {
        float v[16];
#pragma unroll
        for (int j = 0; j < 16; ++j)
            if (k0 + j < NCLS) v[j] = p[(size_t)(5 + k0 + j) * HW];
#pragma unroll
        for (int j = 0; j < 16; ++j)
            if (k0 + j < NCLS) {
                cls  = v[j] > best ? (k0 + j) : cls;
                best = fmaxf(v[j], best);
            }
    }

    const float aw = anc[a * 2 + 0], ah = anc[a * 2 + 1];
    const float conf = sigm(t0);
    const float cx   = ((float)x + sigm(t1)) * t;
    const float cy   = ((float)y + sigm(t2)) * t;
    const float w    = aw * expf(t3);
    const float h    = ah * expf(t4);
    const float x1   = cx - w * 0.5f;
    const float y1   = cy - h * 0.5f;

    // wave writes rows r..r+63: contiguous 1536B of boxes + 256B of valid
    float2* o = reinterpret_cast<float2*>(boxes + (size_t)row * 6);
    o[0] = make_float2(conf, x1);
    o[1] = make_float2(y1, x1 + w);
    o[2] = make_float2(y1 + h, (float)cls);
    valid[row] = conf > th ? 1.0f : 0.0f;
}

__global__ __launch_bounds__(256) void yolo_decode_kernel(
    const float* __restrict__ in13, const float* __restrict__ in26,
    const float* __restrict__ in52,
    const float* __restrict__ a13, const float* __restrict__ a26,
    const float* __restrict__ a52,
    const float* __restrict__ pth, float* __restrict__ out)
{
    const int i = blockIdx.x * blockDim.x + threadIdx.x;
    if (i >= NTOT) return;
    const float th = *pth;
    float* boxes = out;
    float* valid = out + (size_t)NTOT * 6;

    if (i < N13) {
        decode_row<HW13, 13>(in13, a13, 32.0f, i, i, th, boxes, valid);
    } else if (i < N13 + N26) {
        decode_row<HW26, 26>(in26, a26, 16.0f, i - N13, i, th, boxes, valid);
    } else {
        decode_row<HW52, 52>(in52, a52, 8.0f, i - (N13 + N26), i, th, boxes, valid);
    }
}

extern "C" void kernel_launch(void* const* d_in, const int* in_sizes, int n_in,
                              void* d_out, int out_size, void* d_ws, size_t ws_size,
                              hipStream_t stream) {
    const float* in13 = (const float*)d_in[0];
    const float* in26 = (const float*)d_in[1];
    const float* in52 = (const float*)d_in[2];
    const float* a13  = (const float*)d_in[3];
    const float* a26  = (const float*)d_in[4];
    const float* a52  = (const float*)d_in[5];
    const float* pth  = (const float*)d_in[6];
    float* out = (float*)d_out;

    const int block = 256;
    const int grid  = (NTOT + block - 1) / block;
    yolo_decode_kernel<<<grid, block, 0, stream>>>(in13, in26, in52,
                                                   a13, a26, a52, pth, out);
}